// Round 10
// baseline (195.811 us; speedup 1.0000x reference)
//
#include <hip/hip_runtime.h>
#include <hip/hip_bf16.h>

typedef __attribute__((ext_vector_type(8))) short bf16x8;
typedef __attribute__((ext_vector_type(4))) float f32x4;
typedef __attribute__((ext_vector_type(4))) unsigned int u32x4;
typedef __attribute__((ext_vector_type(2))) unsigned int u32x2;

#define B_SZ 4
#define C_SZ 256
#define N_SZ 4096
#define DK_SZ 32

// ws layout in bf16 elements
#define WQB_OFF 0
#define WKB_OFF 8192
#define WVB_OFF 16384
#define QB_OFF  81920
#define KB_OFF  606208
#define VB_OFF  1130496   // V tiled: [b][mblk=n/64][c][64]

__device__ __forceinline__ short f2bf(float f) {
    union { float f; unsigned int u; } v; v.f = f;
    unsigned int r = v.u + 0x7fffu + ((v.u >> 16) & 1u);
    return (short)(r >> 16);
}

__device__ __forceinline__ float asf(unsigned int u) {
    union { unsigned int u; float f; } v; v.u = u;
    return v.f;
}

__device__ __forceinline__ unsigned int cvt_pk_bf16(float lo, float hi) {
    unsigned int r;
    asm volatile("v_cvt_pk_bf16_f32 %0, %1, %2" : "=v"(r) : "v"(lo), "v"(hi));
    return r;
}

__device__ __forceinline__ f32x4 mfma16(bf16x8 a, bf16x8 b, f32x4 c) {
    return __builtin_amdgcn_mfma_f32_16x16x32_bf16(a, b, c, 0, 0, 0);
}

// XCD-affinity remap (k_prep, grid 256): batch b owns XCDs {2b, 2b+1}.
__device__ __forceinline__ void remap_block(int i, int& b, int& n0) {
    b = (i & 7) >> 1;
    n0 = (((i >> 3) << 1) | (i & 1)) * 64;
}

// ---------------- weight conversion ----------------
__global__ __launch_bounds__(256) void k_convw(const float* __restrict__ Wq,
                                               const float* __restrict__ Wk,
                                               const float* __restrict__ Wv,
                                               short* __restrict__ ws) {
    int i = blockIdx.x * 256 + threadIdx.x;
    if (i < 8192) {
        ws[WQB_OFF + i] = f2bf(Wq[i]);
        ws[WKB_OFF + i] = f2bf(Wk[i]);
    }
    ws[WVB_OFF + i] = f2bf(Wv[i]);
}

// ---------------- projection: q, k as [b][n][32] bf16; v TILED [b][mblk][c][64] ----------------
__global__ __launch_bounds__(256) void k_prep(const float* __restrict__ x,
                                              const float* __restrict__ bq,
                                              const float* __restrict__ bk,
                                              const float* __restrict__ bv,
                                              short* __restrict__ ws) {
    __shared__ short xsT[64][264];
    __shared__ short vt_s[64][258];

    int b, n0;
    remap_block(blockIdx.x, b, n0);
    const int t = threadIdx.x;
    const float* xb = x + (size_t)b * C_SZ * N_SZ;

    {
        int c0 = t >> 4, n4 = (t & 15) * 4;
#pragma unroll
        for (int i = 0; i < 16; i++) {
            int c = c0 + 16 * i;
            float4 v = *(const float4*)(xb + (size_t)c * N_SZ + n0 + n4);
            xsT[n4 + 0][c] = f2bf(v.x);
            xsT[n4 + 1][c] = f2bf(v.y);
            xsT[n4 + 2][c] = f2bf(v.z);
            xsT[n4 + 3][c] = f2bf(v.w);
        }
    }
    __syncthreads();

    const int w = t >> 6, l = t & 63;
    const int lr = l & 15, lk = l >> 4;

    bf16x8 af[8];
#pragma unroll
    for (int kk = 0; kk < 8; kk++)
        af[kk] = *(const bf16x8*)(&xsT[w * 16 + lr][kk * 32 + lk * 8]);

#pragma unroll
    for (int qk = 0; qk < 2; qk++) {
        const short* wb = ws + (qk ? WKB_OFF : WQB_OFF);
        const float* bias = qk ? bk : bq;
        short* outp = ws + (qk ? KB_OFF : QB_OFF) + (size_t)b * N_SZ * DK_SZ;
#pragma unroll
        for (int cf = 0; cf < 2; cf++) {
            f32x4 acc = {0.f, 0.f, 0.f, 0.f};
#pragma unroll
            for (int kk = 0; kk < 8; kk++) {
                bf16x8 bfr = *(const bf16x8*)(wb + (cf * 16 + lr) * 256 + kk * 32 + lk * 8);
                acc = mfma16(af[kk], bfr, acc);
            }
            float bias_v = bias[cf * 16 + lr];
#pragma unroll
            for (int r = 0; r < 4; r++) {
                int row = w * 16 + lk * 4 + r;
                outp[(size_t)(n0 + row) * DK_SZ + cf * 16 + lr] = f2bf(acc[r] + bias_v);
            }
        }
    }

#pragma unroll
    for (int cf = 0; cf < 16; cf++) {
        f32x4 acc = {0.f, 0.f, 0.f, 0.f};
#pragma unroll
        for (int kk = 0; kk < 8; kk++) {
            bf16x8 bfr = *(const bf16x8*)(ws + WVB_OFF + (cf * 16 + lr) * 256 + kk * 32 + lk * 8);
            acc = mfma16(af[kk], bfr, acc);
        }
        float bias_v = bv[cf * 16 + lr];
#pragma unroll
        for (int r = 0; r < 4; r++) {
            vt_s[w * 16 + lk * 4 + r][cf * 16 + lr] = f2bf(acc[r] + bias_v);
        }
    }
    __syncthreads();
    {
        // tiled V write: [mblk = n0/64][c][64], contiguous per c -> coalesced
        short* vt = ws + VB_OFF + (size_t)b * C_SZ * N_SZ + (size_t)(n0 >> 6) * (C_SZ * 64);
        int nn = t & 63;
#pragma unroll
        for (int i = 0; i < 64; i++) {
            int c = (t >> 6) + 4 * i;
            vt[c * 64 + nn] = vt_s[nn][c];
        }
    }
}

// ---------------- fused attention (32-row tiles, reg-prefetch, no-drain barriers) ----------------
// Grid 512 (2 blocks/CU), 512 threads = 8 waves, 34 KB LDS, VGPR<=128 -> 4 waves/SIMD.
// SCOMP map: ng=w&1 (16-row n-group), mq=w>>1 (m-16-quarter).
// PV map:    cq=w&3 (64-channel quarter), mh=w>>2 (m-half); V from tiled ws layout.
// Pipeline: V(t+1)/K(t+2) prefetched into alternating REGISTER sets (unroll-2);
// P double-buffered in LDS. Barrier = s_waitcnt lgkmcnt(0) + s_barrier ONLY --
// no vmcnt drain, so prefetches and nt-store acks stay in flight across it.
__global__ __launch_bounds__(512, 4) void k_attn(const short* __restrict__ ws,
                                                 const float* __restrict__ x,
                                                 const float* __restrict__ gamma_p,
                                                 float* __restrict__ out) {
    __shared__ __align__(16) char smem[34816];
    short (*p_lds)[32][72] = (short(*)[32][72])smem;   // [2][32][72] bf16 = 9.2 KB
    float* rsum_s = (float*)(smem + 9216);             // [4][32]

    const int i = blockIdx.x;
    const int b = (i & 7) >> 1;
    const int n0 = (((i >> 3) << 1) | (i & 1)) * 32;

    const int t = threadIdx.x, w = t >> 6, l = t & 63;
    const int lr = l & 15, lk = l >> 4;
    const int ng = w & 1, mq = w >> 1;   // SCOMP / pass-1
    const int cq = w & 3, mh = w >> 2;   // PV

    const short* qb = ws + QB_OFF + (size_t)b * N_SZ * DK_SZ;
    const short* kb = ws + KB_OFF + (size_t)b * N_SZ * DK_SZ;
    const short* vb2 = ws + VB_OFF + (size_t)b * C_SZ * N_SZ;   // tiled [mblk][c][64]

    bf16x8 qf = *(const bf16x8*)(qb + (size_t)(n0 + ng * 16 + lr) * DK_SZ + lk * 8);

    // ---- pass 1: rowsum of exp(S); wave (ng, mq) covers m-quarter mq ----
    float rs = 0.f;
    for (int mt = 0; mt < 16; mt++) {
        int mb = mq * 1024 + mt * 64;
        bf16x8 kfa = *(const bf16x8*)(kb + (size_t)(mb + lr) * DK_SZ + lk * 8);
        bf16x8 kfb = *(const bf16x8*)(kb + (size_t)(mb + 16 + lr) * DK_SZ + lk * 8);
        bf16x8 kfc = *(const bf16x8*)(kb + (size_t)(mb + 32 + lr) * DK_SZ + lk * 8);
        bf16x8 kfd = *(const bf16x8*)(kb + (size_t)(mb + 48 + lr) * DK_SZ + lk * 8);
        f32x4 s0 = mfma16(kfa, qf, (f32x4){0.f, 0.f, 0.f, 0.f});
        f32x4 s1 = mfma16(kfb, qf, (f32x4){0.f, 0.f, 0.f, 0.f});
        f32x4 s2 = mfma16(kfc, qf, (f32x4){0.f, 0.f, 0.f, 0.f});
        f32x4 s3 = mfma16(kfd, qf, (f32x4){0.f, 0.f, 0.f, 0.f});
#pragma unroll
        for (int r = 0; r < 4; r++)
            rs += __expf(s0[r]) + __expf(s1[r]) + __expf(s2[r]) + __expf(s3[r]);
    }
    rs += __shfl_xor(rs, 16);
    rs += __shfl_xor(rs, 32);
    if (l < 16) rsum_s[mq * 32 + ng * 16 + l] = rs;
    __syncthreads();
    const float invp = 1.f / (rsum_s[ng * 16 + lr] + rsum_s[32 + ng * 16 + lr] +
                              rsum_s[64 + ng * 16 + lr] + rsum_s[96 + ng * 16 + lr]);

    float* attn_b = out + (size_t)B_SZ * C_SZ * N_SZ + (size_t)b * N_SZ * N_SZ;
    f32x4 O[4][2];
#pragma unroll
    for (int cf = 0; cf < 4; cf++)
#pragma unroll
        for (int rgi = 0; rgi < 2; rgi++) O[cf][rgi] = (f32x4){0.f, 0.f, 0.f, 0.f};

    bf16x8 AfA[4], AfB[4], kfA, kfB;

#define PREF_V(tt, Afn)                                                             \
    {                                                                               \
        const short* vt = vb2 + (size_t)(tt) * (C_SZ * 64);                         \
        _Pragma("unroll")                                                           \
        for (int cf = 0; cf < 4; cf++)                                              \
            Afn[cf] = *(const bf16x8*)(vt + (cq * 64 + cf * 16 + lr) * 64           \
                                       + mh * 32 + lk * 8);                         \
    }

#define PREF_K(tt, kfn)                                                             \
    kfn = *(const bf16x8*)(kb + (size_t)((tt) * 64 + mq * 16 + lr) * DK_SZ + lk * 8);

    // SCOMP(tt): S-tile via prefetched K -> exp*invp -> p_lds[(tt)&1]
#define SCOMP(tt, kfc)                                                              \
    {                                                                               \
        f32x4 s = mfma16(kfc, qf, (f32x4){0.f, 0.f, 0.f, 0.f});                     \
        u32x2 pk;                                                                   \
        pk[0] = cvt_pk_bf16(__expf(s[0]) * invp, __expf(s[1]) * invp);              \
        pk[1] = cvt_pk_bf16(__expf(s[2]) * invp, __expf(s[3]) * invp);              \
        *(u32x2*)(&p_lds[(tt) & 1][ng * 16 + lr][mq * 16 + lk * 4]) = pk;           \
    }

    // ASTORE(tt): full-line nt stores from p_lds[(tt)&1]
#define ASTORE(tt)                                                                  \
    {                                                                               \
        const int arow = t >> 4;                                                    \
        const int m16 = t & 15;                                                     \
        u32x2 u = *(const u32x2*)(&p_lds[(tt) & 1][arow][m16 * 4]);                 \
        f32x4 f;                                                                    \
        f[0] = asf(u[0] << 16); f[1] = asf(u[0] & 0xffff0000u);                     \
        f[2] = asf(u[1] << 16); f[3] = asf(u[1] & 0xffff0000u);                     \
        __builtin_nontemporal_store(f,                                              \
            (f32x4*)(attn_b + (size_t)(n0 + arow) * N_SZ + (tt) * 64 + m16 * 4));   \
    }

    // PV(tt, Afc): O += V-frags (registers) * P-frags (p_lds[(tt)&1])
#define PV(tt, Afc)                                                                 \
    {                                                                               \
        bf16x8 Bf[2];                                                               \
        _Pragma("unroll")                                                           \
        for (int rgi = 0; rgi < 2; rgi++)                                           \
            Bf[rgi] = *(const bf16x8*)((const char*)&p_lds[(tt) & 1][rgi * 16 + lr][0] \
                                       + mh * 64 + lk * 16);                        \
        _Pragma("unroll")                                                           \
        for (int cf = 0; cf < 4; cf++)                                              \
            _Pragma("unroll")                                                       \
            for (int rgi = 0; rgi < 2; rgi++)                                       \
                O[cf][rgi] = mfma16(Afc[cf], Bf[rgi], O[cf][rgi]);                  \
    }

#define BARRIER()                                                                   \
    asm volatile("s_waitcnt lgkmcnt(0)" ::: "memory");                              \
    __builtin_amdgcn_s_barrier();                                                   \
    __builtin_amdgcn_sched_barrier(0);

#define ITER(tt, Afc, Afn, kfc, kfn)                                                \
    {                                                                               \
        if ((tt) < 63) { PREF_V((tt) + 1, Afn); PREF_K((tt) + 2, kfn); }            \
        ASTORE(tt);                                                                 \
        PV(tt, Afc);                                                                \
        if ((tt) < 63) SCOMP((tt) + 1, kfc);                                        \
        BARRIER();                                                                  \
    }

    // prologue: P(0), V(0), K(1) ready before first iteration
    PREF_K(0, kfA);
    SCOMP(0, kfA);
    PREF_V(0, AfA);
    PREF_K(1, kfA);
    BARRIER();

    for (int mt = 0; mt < 64; mt += 2) {
        ITER(mt, AfA, AfB, kfA, kfB);
        ITER(mt + 1, AfB, AfA, kfB, kfA);
    }
#undef PREF_V
#undef PREF_K
#undef SCOMP
#undef ASTORE
#undef PV
#undef BARRIER
#undef ITER

    // ---- epilogue: reduce mh-pairs through LDS, then out = gamma*O + x ----
    __syncthreads();
    float* o_red = (float*)smem;    // [256 c][32 n], c-stride 33 -> 33.8 KB
    if (mh == 1) {
#pragma unroll
        for (int cf = 0; cf < 4; cf++)
#pragma unroll
            for (int rgi = 0; rgi < 2; rgi++)
#pragma unroll
                for (int r = 0; r < 4; r++)
                    o_red[(cq * 64 + cf * 16 + 4 * lk + r) * 33 + rgi * 16 + lr] = O[cf][rgi][r];
    }
    __syncthreads();
    if (mh == 0) {
#pragma unroll
        for (int cf = 0; cf < 4; cf++)
#pragma unroll
            for (int rgi = 0; rgi < 2; rgi++)
#pragma unroll
                for (int r = 0; r < 4; r++)
                    o_red[(cq * 64 + cf * 16 + 4 * lk + r) * 33 + rgi * 16 + lr] += O[cf][rgi][r];
    }
    __syncthreads();
    {
        const float g = gamma_p[0];
        const float* xb = x + (size_t)b * C_SZ * N_SZ;
        float* ob = out + (size_t)b * C_SZ * N_SZ;
        int nn = t & 31;
        int c0 = t >> 5;   // 0..15
#pragma unroll
        for (int i2 = 0; i2 < 16; i2++) {
            int c = c0 + 16 * i2;
            size_t idx = (size_t)c * N_SZ + n0 + nn;
            ob[idx] = g * o_red[c * 33 + nn] + xb[idx];
        }
    }
}

extern "C" void kernel_launch(void* const* d_in, const int* in_sizes, int n_in,
                              void* d_out, int out_size, void* d_ws, size_t ws_size,
                              hipStream_t stream) {
    const float* x     = (const float*)d_in[0];
    const float* Wq    = (const float*)d_in[1];
    const float* bq    = (const float*)d_in[2];
    const float* Wk    = (const float*)d_in[3];
    const float* bk    = (const float*)d_in[4];
    const float* Wv    = (const float*)d_in[5];
    const float* bv    = (const float*)d_in[6];
    const float* gamma = (const float*)d_in[7];
    short* ws = (short*)d_ws;
    float* out = (float*)d_out;

    hipLaunchKernelGGL(k_convw, dim3(256), dim3(256), 0, stream, Wq, Wk, Wv, ws);
    hipLaunchKernelGGL(k_prep, dim3(256), dim3(256), 0, stream, x, bq, bk, bv, ws);
    hipLaunchKernelGGL(k_attn, dim3(512), dim3(512), 0, stream, ws, x, gamma, out);
}